// Round 4
// baseline (906.471 us; speedup 1.0000x reference)
//
#include <hip/hip_runtime.h>

#define NN 100000
#define NSTEP 5
#define LSTR2 264  // LDS row stride (ushorts): 528B = 33x16B, lane stride 4 dwords -> 2-way free, 16B aligned b128

typedef unsigned short ushort_t;
typedef __attribute__((ext_vector_type(8))) short short8;
typedef __attribute__((ext_vector_type(4))) float floatx4;

__device__ __forceinline__ ushort_t f2bf(float f){
  union { float f; unsigned u; } v; v.f = f;
  unsigned r = v.u + 0x7fffu + ((v.u >> 16) & 1u);
  return (ushort_t)(r >> 16);
}
__device__ __forceinline__ float bf2f(ushort_t s){
  union { unsigned u; float f; } v; v.u = ((unsigned)s) << 16;
  return v.f;
}
__device__ __forceinline__ float sigf(float x){ return 1.0f/(1.0f+__expf(-x)); }

// ================= fused FNN: hfeat = (elu(x@W1+b1))@W2+b2, bf16 out =================
// 782 blocks x 256 thr (4 waves). 128 rows/block, 256 cols. Wave w owns 64-col strip.
// acc[8][4] per wave: 32 MFMAs per kk-iter amortize the 4 global B-loads; B prefetched.
__global__ __launch_bounds__(256, 2) void fnn_fused(const float* __restrict__ x,
    const ushort_t* __restrict__ W1T, const float* __restrict__ b1,
    const ushort_t* __restrict__ W2T, const float* __restrict__ b2,
    ushort_t* __restrict__ hfeat, int M)
{
  __shared__ ushort_t buf[128 * LSTR2];  // 67.6 KB -> 2 blocks/CU
  int tid = threadIdx.x;
  int w = tid >> 6, lane = tid & 63, qd = lane >> 4, r16 = lane & 15;
  int row0 = blockIdx.x * 128;
  int col0 = w * 64;

  // ---- stage x tile (128x256 fp32 -> bf16 LDS), fully linear/coalesced ----
  #pragma unroll
  for (int it = 0; it < 32; it++){
    int idx = it * 256 + tid;            // float4 index within 128x64 grid
    int r = idx >> 6, c4 = idx & 63;
    int rg = row0 + r; if (rg >= M) rg = M - 1;
    float4 v = *(const float4*)(x + (size_t)rg * 256 + c4 * 4);
    ushort4 pk = make_ushort4(f2bf(v.x), f2bf(v.y), f2bf(v.z), f2bf(v.w));
    *(ushort4*)&buf[r * LSTR2 + c4 * 4] = pk;
  }
  __syncthreads();

  floatx4 acc[8][4];

  // ---- GEMM1: t = x @ W1T^T ----
  #pragma unroll
  for (int i=0;i<8;i++)
    #pragma unroll
    for (int j=0;j<4;j++) acc[i][j] = (floatx4){0.f,0.f,0.f,0.f};

  {
    short8 bn[4];
    #pragma unroll
    for (int j=0;j<4;j++)
      bn[j] = *(const short8*)(W1T + (size_t)(col0 + j*16 + r16) * 256 + qd*8);
    #pragma unroll
    for (int kk = 0; kk < 256; kk += 32){
      short8 bc[4];
      #pragma unroll
      for (int j=0;j<4;j++) bc[j] = bn[j];
      if (kk < 224){
        #pragma unroll
        for (int j=0;j<4;j++)
          bn[j] = *(const short8*)(W1T + (size_t)(col0 + j*16 + r16) * 256 + kk + 32 + qd*8);
      }
      short8 af[8];
      #pragma unroll
      for (int i=0;i<8;i++)
        af[i] = *(const short8*)&buf[(i*16 + r16) * LSTR2 + kk + qd*8];
      #pragma unroll
      for (int i=0;i<8;i++)
        #pragma unroll
        for (int j=0;j<4;j++)
          acc[i][j] = __builtin_amdgcn_mfma_f32_16x16x32_bf16(af[i], bc[j], acc[i][j], 0, 0, 0);
    }
  }
  __syncthreads();

  // ---- ELU + bf16 -> t tile in same LDS buffer ----
  #pragma unroll
  for (int i=0;i<8;i++){
    #pragma unroll
    for (int j=0;j<4;j++){
      int col = col0 + j*16 + r16;
      float bb = b1[col];
      #pragma unroll
      for (int rr=0;rr<4;rr++){
        int row = i*16 + qd*4 + rr;
        float v = acc[i][j][rr] + bb;
        v = v > 0.f ? v : expm1f(v);
        buf[row * LSTR2 + col] = f2bf(v);
      }
    }
  }
  __syncthreads();

  // ---- GEMM2: hfeat = t @ W2T^T (reuse acc) ----
  #pragma unroll
  for (int i=0;i<8;i++)
    #pragma unroll
    for (int j=0;j<4;j++) acc[i][j] = (floatx4){0.f,0.f,0.f,0.f};

  {
    short8 bn[4];
    #pragma unroll
    for (int j=0;j<4;j++)
      bn[j] = *(const short8*)(W2T + (size_t)(col0 + j*16 + r16) * 256 + qd*8);
    #pragma unroll
    for (int kk = 0; kk < 256; kk += 32){
      short8 bc[4];
      #pragma unroll
      for (int j=0;j<4;j++) bc[j] = bn[j];
      if (kk < 224){
        #pragma unroll
        for (int j=0;j<4;j++)
          bn[j] = *(const short8*)(W2T + (size_t)(col0 + j*16 + r16) * 256 + kk + 32 + qd*8);
      }
      short8 af[8];
      #pragma unroll
      for (int i=0;i<8;i++)
        af[i] = *(const short8*)&buf[(i*16 + r16) * LSTR2 + kk + qd*8];
      #pragma unroll
      for (int i=0;i<8;i++)
        #pragma unroll
        for (int j=0;j<4;j++)
          acc[i][j] = __builtin_amdgcn_mfma_f32_16x16x32_bf16(af[i], bc[j], acc[i][j], 0, 0, 0);
    }
  }

  // ---- epilogue: bf16 store ----
  #pragma unroll
  for (int i=0;i<8;i++){
    #pragma unroll
    for (int j=0;j<4;j++){
      int col = col0 + j*16 + r16;
      float bb = b2[col];
      #pragma unroll
      for (int rr=0;rr<4;rr++){
        int row = row0 + i*16 + qd*4 + rr;
        if (row < M) hfeat[(size_t)row * 256 + col] = f2bf(acc[i][j][rr] + bb);
      }
    }
  }
}

// ================= fused LSTM layer: gates GEMM (K-split x4) + cell pointwise =================
__global__ __launch_bounds__(256) void lstm_layer(const ushort_t* __restrict__ A, int lda,
    const ushort_t* __restrict__ Wc, const float* __restrict__ bc, int K,
    float* __restrict__ c, ushort_t* __restrict__ dstA, int sA,
    ushort_t* __restrict__ dstB, int sB, float* __restrict__ qdst)
{
  __shared__ float sbuf[3][4][256];
  int tid = threadIdx.x, w = tid >> 6, lane = tid & 63, qd = lane >> 4, r16 = lane & 15;
  int m0 = (blockIdx.x & 7) * 16, n0 = (blockIdx.x >> 3) * 16;
  int kq = K >> 2;
  int kbeg = w * kq, kend = kbeg + kq;

  floatx4 acc[4];
  #pragma unroll
  for (int g=0; g<4; g++) acc[g] = (floatx4){0.f,0.f,0.f,0.f};

  const ushort_t* Ar = A + (size_t)(m0 + r16) * lda + qd * 8;
  for (int kk = kbeg; kk < kend; kk += 32){
    short8 av = *(const short8*)(Ar + kk);
    #pragma unroll
    for (int g = 0; g < 4; g++){
      short8 bv = *(const short8*)(Wc + (size_t)(g*256 + n0 + r16) * K + kk + qd*8);
      acc[g] = __builtin_amdgcn_mfma_f32_16x16x32_bf16(av, bv, acc[g], 0, 0, 0);
    }
  }

  if (w){
    #pragma unroll
    for (int g=0; g<4; g++) *(floatx4*)&sbuf[w-1][g][lane*4] = acc[g];
  }
  __syncthreads();
  if (w == 0){
    #pragma unroll
    for (int g=0; g<4; g++)
      #pragma unroll
      for (int t=0; t<3; t++){
        floatx4 p = *(floatx4*)&sbuf[t][g][lane*4];
        acc[g][0]+=p[0]; acc[g][1]+=p[1]; acc[g][2]+=p[2]; acc[g][3]+=p[3];
      }
    int h = n0 + r16;
    float bci = bc[h], bcf = bc[256+h], bcg = bc[512+h], bco = bc[768+h];
    #pragma unroll
    for (int rr=0; rr<4; rr++){
      int row = m0 + qd*4 + rr;
      float gi = acc[0][rr] + bci;
      float gf = acc[1][rr] + bcf;
      float gg = acc[2][rr] + bcg;
      float go = acc[3][rr] + bco;
      float cp = c[row*256 + h];
      float cn = sigf(gf)*cp + sigf(gi)*tanhf(gg);
      float hn = sigf(go)*tanhf(cn);
      c[row*256 + h] = cn;
      ushort_t hb = f2bf(hn);
      dstA[row*sA + h] = hb;
      dstB[row*sB + h] = hb;
      if (qdst) qdst[row*512 + h] = hn;
    }
  }
}

// ================= fused attention: e -> softmax -> r, one block per segment =================
// 128 blocks x 1024 threads (16 waves). e cached in LDS (2048 cap, global fallback).
__global__ __launch_bounds__(1024) void attn_post(const ushort_t* __restrict__ hfeat,
    const int* __restrict__ seg, float* __restrict__ q_star, ushort_t* __restrict__ xc0,
    float* __restrict__ e_ws)
{
  int b = blockIdx.x;
  int s = seg[b], en = seg[b+1], cnt = en - s;
  int tid = threadIdx.x, lane = tid & 63, w = tid >> 6;

  __shared__ float qld[256];
  __shared__ float els[2048];
  __shared__ float red[16];
  __shared__ float prt[4][256];
  __shared__ float mss, iss;

  if (tid < 256) qld[tid] = q_star[b*512 + tid];
  __syncthreads();

  // ---- phase 1: e[n] = dot(hfeat[n], q), one wave per row ----
  float lmax = -INFINITY;
  for (int i = w; i < cnt; i += 16){
    int n = s + i;
    ushort4 hv = *(const ushort4*)(hfeat + (size_t)n*256 + lane*4);
    const float* qp = &qld[lane*4];
    float d = bf2f(hv.x)*qp[0] + bf2f(hv.y)*qp[1] + bf2f(hv.z)*qp[2] + bf2f(hv.w)*qp[3];
    #pragma unroll
    for (int off = 32; off; off >>= 1) d += __shfl_xor(d, off);
    if (lane == 0){
      if (i < 2048) els[i] = d;
      else e_ws[n] = d;
    }
    lmax = fmaxf(lmax, d);
  }
  if (lane == 0) red[w] = lmax;
  __syncthreads();
  if (tid == 0){
    float m = -INFINITY;
    #pragma unroll
    for (int i=0;i<16;i++) m = fmaxf(m, red[i]);
    if (cnt == 0) m = 0.f;
    mss = m;
  }
  __syncthreads();
  float m = mss;

  // ---- phase 2: sum of exp, then normalize LDS e -> a in place ----
  float ls = 0.f;
  for (int i = tid; i < cnt; i += 1024){
    float e = (i < 2048) ? els[i] : e_ws[s+i];
    ls += __expf(e - m);
  }
  #pragma unroll
  for (int off = 32; off; off >>= 1) ls += __shfl_xor(ls, off);
  if (lane == 0) red[w] = ls;
  __syncthreads();
  if (tid == 0){
    float sum = 1e-16f;
    #pragma unroll
    for (int i=0;i<16;i++) sum += red[i];
    iss = 1.0f / sum;
  }
  __syncthreads();
  float inv = iss;
  int ncap = cnt < 2048 ? cnt : 2048;
  for (int i = tid; i < ncap; i += 1024) els[i] = __expf(els[i] - m) * inv;
  __syncthreads();

  // ---- phase 3: r[f] = sum a[n]*hfeat[n][f]; thread = (rowgroup, feature) ----
  int f = tid & 255, rg = tid >> 8;
  float acc = 0.f;
  for (int i = rg; i < cnt; i += 4){
    float a = (i < 2048) ? els[i] : (__expf(e_ws[s+i] - m) * inv);
    acc += a * bf2f(hfeat[(size_t)(s+i)*256 + f]);
  }
  prt[rg][f] = acc;
  __syncthreads();
  if (tid < 256){
    float r = prt[0][tid] + prt[1][tid] + prt[2][tid] + prt[3][tid];
    q_star[b*512 + 256 + tid] = r;
    xc0[b*768 + 256 + tid] = f2bf(r);
  }
}

// ================= final: out(128,128) = q_star(128,512) @ outW + outb =================
__global__ __launch_bounds__(128) void final_k(const float* __restrict__ q_star,
    const float* __restrict__ W, const float* __restrict__ bias, float* __restrict__ out)
{
  __shared__ float qs[512];
  int b = blockIdx.x, e = threadIdx.x;
  #pragma unroll
  for (int i = 0; i < 4; i++) qs[e + i*128] = q_star[b*512 + e + i*128];
  __syncthreads();
  float acc = bias[e];
  for (int k = 0; k < 512; k++) acc += qs[k] * W[k*128 + e];
  out[b*128 + e] = acc;
}

// ================= prep: weight bf16 conversion/packing =================
__global__ void prep_w(const float* __restrict__ W1, const float* __restrict__ W2,
    const float* __restrict__ Wih0, const float* __restrict__ Whh0,
    const float* __restrict__ Wih1, const float* __restrict__ Whh1,
    const float* __restrict__ Wih2, const float* __restrict__ Whh2,
    ushort_t* __restrict__ W1T, ushort_t* __restrict__ W2T,
    ushort_t* __restrict__ Wc0, ushort_t* __restrict__ Wc1, ushort_t* __restrict__ Wc2)
{
  int i = blockIdx.x*256 + threadIdx.x;
  if (i < 65536){                       // W1T[n,k] = W1[k,n]
    W1T[i] = f2bf(W1[(i & 255)*256 + (i >> 8)]);
  } else if (i < 131072){
    int j = i - 65536;
    W2T[j] = f2bf(W2[(j & 255)*256 + (j >> 8)]);
  } else if (i < 131072 + 786432){      // Wc0[g, 0:512]=Wih0, [512:768]=Whh0
    int j = i - 131072;
    int g = j / 768, k = j - g*768;
    Wc0[j] = f2bf(k < 512 ? Wih0[g*512 + k] : Whh0[g*256 + (k - 512)]);
  } else if (i < 131072 + 786432 + 524288){
    int j = i - (131072 + 786432);
    int g = j >> 9, k = j & 511;
    Wc1[j] = f2bf(k < 256 ? Wih1[g*256 + k] : Whh1[g*256 + (k - 256)]);
  } else if (i < 131072 + 786432 + 1048576){
    int j = i - (131072 + 786432 + 524288);
    int g = j >> 9, k = j & 511;
    Wc2[j] = f2bf(k < 256 ? Wih2[g*256 + k] : Whh2[g*256 + (k - 256)]);
  }
}

// ================= prep: zeros + combined biases + segment bounds =================
__global__ void prep_misc(const float* __restrict__ bih0, const float* __restrict__ bhh0,
    const float* __restrict__ bih1, const float* __restrict__ bhh1,
    const float* __restrict__ bih2, const float* __restrict__ bhh2,
    const int* __restrict__ bidx,
    float* __restrict__ c, ushort_t* __restrict__ xc, float* __restrict__ q_star,
    float* __restrict__ bc, int* __restrict__ seg)
{
  int i = blockIdx.x*256 + threadIdx.x;
  if (i < 98304) { c[i] = 0.f; return; }
  i -= 98304;
  if (i < 229376) { xc[i] = 0; return; }
  i -= 229376;
  if (i < 65536) { q_star[i] = 0.f; return; }
  i -= 65536;
  if (i < 3072) {
    int l = i >> 10, g = i & 1023;
    const float* bi = (l == 0) ? bih0 : ((l == 1) ? bih1 : bih2);
    const float* bh = (l == 0) ? bhh0 : ((l == 1) ? bhh1 : bhh2);
    bc[i] = bi[g] + bh[g];
    return;
  }
  i -= 3072;
  if (i < 129) {
    int lo = 0, hi = NN;
    while (lo < hi){ int mid = (lo + hi) >> 1; if (bidx[mid] < i) lo = mid + 1; else hi = mid; }
    seg[i] = lo;
  }
}

extern "C" void kernel_launch(void* const* d_in, const int* in_sizes, int n_in,
                              void* d_out, int out_size, void* d_ws, size_t ws_size,
                              hipStream_t stream)
{
  const float* x    = (const float*)d_in[0];
  const int*   bidx = (const int*)  d_in[1];
  const float* W1   = (const float*)d_in[2];
  const float* b1   = (const float*)d_in[3];
  const float* W2   = (const float*)d_in[4];
  const float* b2   = (const float*)d_in[5];
  const float* Wih0 = (const float*)d_in[6];
  const float* Whh0 = (const float*)d_in[7];
  const float* bih0 = (const float*)d_in[8];
  const float* bhh0 = (const float*)d_in[9];
  const float* Wih1 = (const float*)d_in[10];
  const float* Whh1 = (const float*)d_in[11];
  const float* bih1 = (const float*)d_in[12];
  const float* bhh1 = (const float*)d_in[13];
  const float* Wih2 = (const float*)d_in[14];
  const float* Whh2 = (const float*)d_in[15];
  const float* bih2 = (const float*)d_in[16];
  const float* bhh2 = (const float*)d_in[17];
  const float* outW = (const float*)d_in[18];
  const float* outb = (const float*)d_in[19];

  char* p = (char*)d_ws;
  auto alloc = [&](size_t bytes)->char*{ char* r = p; p += (bytes + 255) & ~(size_t)255; return r; };
  ushort_t* hfeat  = (ushort_t*)alloc((size_t)NN*256*2);   // bf16 node features
  float*    e_ws   = (float*)   alloc((size_t)NN*4);       // overflow scratch for attn_post
  ushort_t* W1T    = (ushort_t*)alloc(65536*2);
  ushort_t* W2T    = (ushort_t*)alloc(65536*2);
  ushort_t* Wc0    = (ushort_t*)alloc(786432*2);
  ushort_t* Wc1    = (ushort_t*)alloc(524288*2);
  ushort_t* Wc2    = (ushort_t*)alloc(524288*2);
  float*    bc     = (float*)   alloc(3072*4);
  float*    c_all  = (float*)   alloc(98304*4);
  ushort_t* xc     = (ushort_t*)alloc(229376*2);           // xc0(128x768) | xc1(128x512) | xc2(128x512)
  float*    q_star = (float*)   alloc(65536*4);            // (128, 512) fp32
  int*      seg    = (int*)     alloc(129*4);

  ushort_t* xc0 = xc;
  ushort_t* xc1 = xc + 98304;
  ushort_t* xc2 = xc + 163840;
  float* c0 = c_all, *c1 = c_all + 32768, *c2 = c_all + 65536;
  float* bc0 = bc, *bc1 = bc + 1024, *bc2 = bc + 2048;

  prep_w<<<7680, 256, 0, stream>>>(W1, W2, Wih0, Whh0, Wih1, Whh1, Wih2, Whh2,
                                   W1T, W2T, Wc0, Wc1, Wc2);
  prep_misc<<<1549, 256, 0, stream>>>(bih0, bhh0, bih1, bhh1, bih2, bhh2, bidx,
                                      c_all, xc, q_star, bc, seg);

  fnn_fused<<<782, 256, 0, stream>>>(x, W1T, b1, W2T, b2, hfeat, NN);

  for (int s = 0; s < NSTEP; s++){
    // layer 0: in = [q_star | h0_prev] (K=768)
    lstm_layer<<<128, 256, 0, stream>>>(xc0, 768, Wc0, bc0, 768, c0, xc0 + 512, 768, xc1, 512, nullptr);
    // layer 1: in = [h0 | h1_prev] (K=512)
    lstm_layer<<<128, 256, 0, stream>>>(xc1, 512, Wc1, bc1, 512, c1, xc1 + 256, 512, xc2, 512, nullptr);
    // layer 2: in = [h1 | h2_prev] (K=512); h2 = q
    lstm_layer<<<128, 256, 0, stream>>>(xc2, 512, Wc2, bc2, 512, c2, xc2 + 256, 512, xc0, 768, q_star);
    // fused attention: e -> softmax -> r -> q_star/xc0
    attn_post<<<128, 1024, 0, stream>>>(hfeat, seg, q_star, xc0, e_ws);
  }

  final_k<<<128, 128, 0, stream>>>(q_star, outW, outb, (float*)d_out);
}